// Round 4
// baseline (230.634 us; speedup 1.0000x reference)
//
#include <hip/hip_runtime.h>
#include <hip/hip_bf16.h>

#define TT 16      // in_length
#define EE 32      // embedding size
#define HH 64      // encoder size
#define NGRP 32    // vehicles per group
#define CC 3       // classes

typedef __attribute__((ext_vector_type(8))) short short8;
typedef __attribute__((ext_vector_type(4))) float floatx4;

#define MFMA16(a, b, c) __builtin_amdgcn_mfma_f32_16x16x32_bf16((a), (b), (c), 0, 0, 0)

#define RLN2 1.4426950408889634f   // 1/ln2

__device__ __forceinline__ float leakyf(float x) { return fmaxf(x, 0.1f * x); }
__device__ __forceinline__ short f2bf(float x) {   // fp32 -> bf16 RNE (one-time weights)
    unsigned u = __float_as_uint(x);
    return (short)((u + 0x7FFFu + ((u >> 16) & 1u)) >> 16);
}
__device__ __forceinline__ short f2bf_h(float x) { // fp32 -> bf16 round-half-up (per-step)
    return (short)((__float_as_uint(x) + 0x8000u) >> 16);
}
__device__ __forceinline__ float bf2f(short s) {
    return __uint_as_float(((unsigned)(unsigned short)s) << 16);
}
__device__ __forceinline__ short8 ld8bfs(const float* __restrict__ p, float s) {
    const float4 a = *(const float4*)p;
    const float4 b = *(const float4*)(p + 4);
    short8 v;
    v[0] = f2bf(a.x * s); v[1] = f2bf(a.y * s); v[2] = f2bf(a.z * s); v[3] = f2bf(a.w * s);
    v[4] = f2bf(b.x * s); v[5] = f2bf(b.y * s); v[6] = f2bf(b.z * s); v[7] = f2bf(b.w * s);
    return v;
}

// ---------------------------------------------------------------------------
// ONE fused kernel. Block g = scene group g. 512 threads = 8 waves.
//
// R11: register-diet occupancy. Evidence ledger:
//   * R2: LDS 53760->40960 (4-block capable), dur UNCHANGED, Occupancy stuck
//     38% -> LDS was never the residency cap.
//   * R3: VALU ops -21% (VALUBusy 69->55), dur UNCHANGED(+4%) -> VALU
//     throughput is not the critical path. (Packed-math reverted: it cost 4%.)
//   * R1: launch_bounds(512,8) -> Occupancy 83% (the ONLY round >38%), proving
//     the allocator obeys the budget; but 64 total regs spilled the B-frags.
//   Reconciliation: rocprof VGPR_Count=64 EXCLUDES AGPRs. True unified usage
//   = ~128/lane -> 4 waves/SIMD -> 2 blocks/CU in every fast round. The
//   binding residency cap is REGISTERS, not LDS.
// This round: __launch_bounds__(512,6) -> budget 85 unified regs/lane ->
// 6 waves/SIMD -> 3 blocks/CU (LDS 40960*3 = 120KB fits). GRU live set
// (9 B-frags 36 + h_reg 8 + biases/addr ~12 + transients ~28 = ~84) should
// just fit where R1's 64 could not.
// Sentinels: FETCH_SIZE >> 10 MB => spilled (shrink B-frag live set next);
// occupancy up but dur flat => per-wave latency chain is the floor
// (=> barrier-free GRU via intra-wave transpose next).
//
// LDS layout (40960 B): Hf single-buffered (2 barriers/step); scene staged
// transiently in Hf bytes pre-loop, re-gathered from L2 post-loop.
// Phase 1 (GRU): waves 0-3 fwd, 4-7 bwd; wave wd owns gate cols [16wd,16wd+16).
//   B-frags pre-scaled by -1/ln2 (r,z) / 2/ln2 (n); biases added as scalars
//   after the MFMA. sigma(x)=rcp(1+exp2(-x/ln2)), tanh(t)=1-2*rcp(exp2(2t/ln2)+1).
//   Hf write slot permuted (slot = qa*16 + r*4 + quad); reads use rlane.
// Phase 2 (spatial MFMA) + Phase 3 (head): R6 structure; spatial arrays
//   overlay dead Xall in a union; Hf region preserved for epilogue.
// ---------------------------------------------------------------------------
__global__ __launch_bounds__(512, 6) void fused_kernel(
    const float* __restrict__ scene, const int* __restrict__ index_div,
    const float* __restrict__ W_emb, const float* __restrict__ b_emb,
    const float* __restrict__ Wih_f, const float* __restrict__ Whh_f,
    const float* __restrict__ bih_f, const float* __restrict__ bhh_f,
    const float* __restrict__ Wih_b, const float* __restrict__ Whh_b,
    const float* __restrict__ bih_b, const float* __restrict__ bhh_b,
    const float* __restrict__ Wm, const float* __restrict__ bm,
    const float* __restrict__ Ws1, const float* __restrict__ bs1,
    const float* __restrict__ Ws2, const float* __restrict__ bs2,
    const float* __restrict__ Wo1, const float* __restrict__ bo1,
    const float* __restrict__ Wo2, const float* __restrict__ bo2,
    float* __restrict__ full_enc, float* __restrict__ out)
{
    __shared__ __align__(16) union SmemU {
        struct {                                     // GRU phase: 40960 B exactly
            short Xall[16 * 2 * 64 * 8];             // [t][mt][lane][8]      32768 B
            short Hf[2 * 2 * 2 * 64 * 8];            // [dir][ks][mt][slot][8] 8192 B (single buf)
        } g;
        struct {                                     // spatial/head phase (25856 B < 32768 B)
            float su[NGRP][68];                      //  8704 B
            float fe[NGRP][68];                      //  8704 B
            float swo1[1024];                        //  4096 B
            float szero[32];                         //   128 B
            float sscene2[32][33];                   //  4224 B  (re-gathered scene, [c][veh])
        } s;
    } sm;

    const int g    = blockIdx.x;
    const int tid  = threadIdx.x;
    const int lane = tid & 63;
    const int w    = __builtin_amdgcn_readfirstlane(tid >> 6);  // 0..7
    const int dir  = w >> 2;
    const int wd   = w & 3;
    const int cc   = lane & 15;
    const int quad = lane >> 4;
    const int j    = wd * 16 + cc;            // gate column
    const int ks_w = j >> 5;
    const int qa_w = (j >> 3) & 3;
    const int ii_w = j & 7;
    // permuted reader lane: slot(Lq, m) = Lq*16 + (m&3)*4 + (m>>2)
    const int rlane = (lane & 48) | ((lane & 3) << 2) | ((lane >> 2) & 3);

    // ---- stage gathered scene rows into the (not-yet-live) Hf bytes as
    //      float sc0[32][33] (4224 B <= 8192 B) ----
    {
        float* sc0 = (float*)sm.g.Hf;
        #pragma unroll
        for (int rep = 0; rep < 2; ++rep) {
            const int idx = tid + rep * 512;
            const int v = idx >> 5, c = idx & 31;
            const int n = index_div[g * NGRP + v];
            sc0[c * 33 + v] = scene[n * 32 + c];
        }
    }

    // ---- per-wave GRU B-frags, pre-scaled; biases stay SCALAR ----
    const float* Wih = dir ? Wih_b : Wih_f;
    const float* Whh = dir ? Whh_b : Whh_f;
    const float* bih = dir ? bih_b : bih_f;
    const float* bhh = dir ? bhh_b : bhh_f;
    const int k0 = quad * 8;
    const float SRZ = -RLN2, SN = 2.0f * RLN2;
    const short8 Br0  = ld8bfs(Whh + (j      ) * 64 + k0,      SRZ);
    const short8 Br1  = ld8bfs(Whh + (j      ) * 64 + 32 + k0, SRZ);
    const short8 Br2  = ld8bfs(Wih + (j      ) * 32 + k0,      SRZ);
    const short8 Bz0  = ld8bfs(Whh + (j +  64) * 64 + k0,      SRZ);
    const short8 Bz1  = ld8bfs(Whh + (j +  64) * 64 + 32 + k0, SRZ);
    const short8 Bz2  = ld8bfs(Wih + (j +  64) * 32 + k0,      SRZ);
    const short8 Bhn0 = ld8bfs(Whh + (j + 128) * 64 + k0,      SN);
    const short8 Bhn1 = ld8bfs(Whh + (j + 128) * 64 + 32 + k0, SN);
    const short8 Bxn  = ld8bfs(Wih + (j + 128) * 32 + k0,      SN);
    const float vb_r  = SRZ * (bih[j] + bhh[j]);
    const float vb_z  = SRZ * (bih[j + 64] + bhh[j + 64]);
    const float vb_xn = SN * bih[j + 128];
    const float vb_hn = SN * bhh[j + 128];

    __syncthreads();   // sc0 ready

    // ---- emb for ALL t (512 threads = 16 t x 32 veh); reads sc0 (in Hf
    //      bytes), writes Xall only. Barrier, THEN zero Hf. ----
    {
        const float* sc0 = (const float*)sm.g.Hf;
        const int t   = tid >> 5;
        const int veh = tid & 31;
        const float xs = sc0[t * 33 + veh];
        const float ys = sc0[(16 + t) * 33 + veh];
        const int mt = veh >> 4;
        const int m  = veh & 15;
        #pragma unroll
        for (int q = 0; q < 4; ++q) {
            short8 v;
            #pragma unroll
            for (int i2 = 0; i2 < 8; ++i2) {
                const int e = q * 8 + i2;
                v[i2] = f2bf(leakyf(fmaf(xs, W_emb[e], fmaf(ys, W_emb[EE + e], b_emb[e]))));
            }
            *(short8*)&sm.g.Xall[(((t * 2 + mt) * 64) + q * 16 + m) * 8] = v;
        }
    }
    __syncthreads();   // all sc0 reads consumed -> Hf bytes reusable
    {
        const short8 z8 = {0, 0, 0, 0, 0, 0, 0, 0};
        *(short8*)&sm.g.Hf[tid * 8] = z8;     // zero all 4096 shorts (both dirs)
    }

    float h_reg[8];
    #pragma unroll
    for (int i = 0; i < 8; ++i) h_reg[i] = 0.0f;

    const int hf_dir = dir * 2048;                 // shorts (dir stride, single buf)
    __syncthreads();   // Hf zeroed

    // ---- GRU main loop: single-buffered Hf, TWO barriers per step ----
    #pragma unroll 2
    for (int s = 0; s < TT; ++s) {
        const int t  = dir ? (TT - 1 - s) : s;
        const short* HfD = &sm.g.Hf[hf_dir];
        #pragma unroll
        for (int mt = 0; mt < 2; ++mt) {
            const short8 Ah0 = *(const short8*)&HfD[((0 * 2 + mt) * 64 + rlane) * 8];
            const short8 Ah1 = *(const short8*)&HfD[((1 * 2 + mt) * 64 + rlane) * 8];
            const short8 Axx = *(const short8*)&sm.g.Xall[((t * 2 + mt) * 64 + lane) * 8];
            const floatx4 z4 = {0.f, 0.f, 0.f, 0.f};
            const floatx4 ar  = MFMA16(Axx, Br2, MFMA16(Ah1, Br1, MFMA16(Ah0, Br0, z4)));
            const floatx4 az  = MFMA16(Axx, Bz2, MFMA16(Ah1, Bz1, MFMA16(Ah0, Bz0, z4)));
            const floatx4 ahn = MFMA16(Ah1, Bhn1, MFMA16(Ah0, Bhn0, z4));
            const floatx4 axn = MFMA16(Axx, Bxn, z4);
            #pragma unroll
            for (int r = 0; r < 4; ++r) {
                // ar = -pre_r/ln2 (pre-scaled); rr = sigmoid(pre_r)
                const float rr = __builtin_amdgcn_rcpf(1.0f + __builtin_amdgcn_exp2f(ar[r] + vb_r));
                const float zz = __builtin_amdgcn_rcpf(1.0f + __builtin_amdgcn_exp2f(az[r] + vb_z));
                // y = 2*(xn + rr*hn)/ln2 ; ng = tanh(xn + rr*hn)
                const float y  = fmaf(rr, ahn[r] + vb_hn, axn[r] + vb_xn);
                const float ng = fmaf(-2.0f,
                                      __builtin_amdgcn_rcpf(__builtin_amdgcn_exp2f(y) + 1.0f),
                                      1.0f);
                const float h0 = h_reg[mt * 4 + r];
                h_reg[mt * 4 + r] = fmaf(zz, h0 - ng, ng);  // (1-z)*ng + z*h
            }
        }
        __syncthreads();   // all waves' Hf reads complete -> in-place write safe
        short* HfW = &sm.g.Hf[hf_dir];
        #pragma unroll
        for (int mt = 0; mt < 2; ++mt) {
            #pragma unroll
            for (int r = 0; r < 4; ++r) {
                const int slot = qa_w * 16 + r * 4 + quad;   // perm of qa*16 + m
                HfW[((ks_w * 2 + mt) * 64 + slot) * 8 + ii_w] = f2bf_h(h_reg[mt * 4 + r]);
            }
        }
        __syncthreads();   // writes visible for next step
    }
    // Final h in Hf[dir]. Xall dead from here.

    // ---- re-gather scene into spatial union region (L2-hot; HBM idle) ----
    #pragma unroll
    for (int rep = 0; rep < 2; ++rep) {
        const int idx = tid + rep * 512;
        const int v = idx >> 5, c = idx & 31;
        const int n = index_div[g * NGRP + v];
        sm.s.sscene2[c][v] = scene[n * 32 + c];
    }
    __syncthreads();   // sscene2 ready

    // ---- Phase 2 prep: waves 0-3 seq_enc epilogue; waves 4-7 su/swo1/szero ----
    if (w < 4) {
        const int nt   = w >> 1;
        const int mt_e = w & 1;
        const int n_col = nt * 16 + cc;
        short8 Bm0, Bm1;
        #pragma unroll
        for (int i = 0; i < 8; ++i) {
            Bm0[i] = f2bf(Wm[(     quad * 8 + i) * 32 + n_col]);
            Bm1[i] = f2bf(Wm[(32 + quad * 8 + i) * 32 + n_col]);
        }
        short8 A0, A1;
        #pragma unroll
        for (int ks = 0; ks < 2; ++ks) {
            const short8 F = *(const short8*)&sm.g.Hf[0    + ((ks * 2 + mt_e) * 64 + rlane) * 8];
            const short8 B = *(const short8*)&sm.g.Hf[2048 + ((ks * 2 + mt_e) * 64 + rlane) * 8];
            #pragma unroll
            for (int i = 0; i < 8; ++i) {
                const short v = f2bf(0.5f * (bf2f(F[i]) + bf2f(B[i])));
                if (ks == 0) A0[i] = v; else A1[i] = v;
            }
        }
        const floatx4 z4 = {0.f, 0.f, 0.f, 0.f};
        const floatx4 acc = MFMA16(A1, Bm1, MFMA16(A0, Bm0, z4));
        const float bmn = bm[n_col];
        #pragma unroll
        for (int r = 0; r < 4; ++r) {
            const int veh = mt_e * 16 + quad * 4 + r;
            const float sv = leakyf(acc[r] + bmn);
            const int n = index_div[g * NGRP + veh];
            full_enc[n * HH + n_col] = sv;
            sm.s.fe[veh][n_col] = sv;     // fe region does not overlap Hf
        }
    } else {
        const int l  = tid & 255;
        const int v  = l >> 3;
        const int d0 = (l & 7) * 8;
        float acc[8];
        #pragma unroll
        for (int i = 0; i < 8; ++i) acc[i] = 0.0f;
        #pragma unroll
        for (int e = 0; e < EE; ++e) {
            const float f = sm.s.sscene2[e][v];
            const float4 w0 = *(const float4*)&Ws1[e * 64 + d0];
            const float4 w1 = *(const float4*)&Ws1[e * 64 + d0 + 4];
            acc[0] = fmaf(f, w0.x, acc[0]); acc[1] = fmaf(f, w0.y, acc[1]);
            acc[2] = fmaf(f, w0.z, acc[2]); acc[3] = fmaf(f, w0.w, acc[3]);
            acc[4] = fmaf(f, w1.x, acc[4]); acc[5] = fmaf(f, w1.y, acc[5]);
            acc[6] = fmaf(f, w1.z, acc[6]); acc[7] = fmaf(f, w1.w, acc[7]);
        }
        #pragma unroll
        for (int i = 0; i < 8; ++i) sm.s.su[v][d0 + i] = acc[i];
        *(float4*)&sm.s.swo1[l * 4] = *(const float4*)&Wo1[l * 4];
        if (l < 32) {
            float zs = bs2[l];
            #pragma unroll
            for (int d = 0; d < HH; ++d) zs = fmaf(leakyf(bs1[d]), Ws2[d * 32 + l], zs);
            sm.s.szero[l] = leakyf(zs);
        }
    }

    // ---- spatial B-frags (all 8 waves) ----
    short8 Bw00, Bw01, Bw10, Bw11;
    #pragma unroll
    for (int i = 0; i < 8; ++i) {
        Bw00[i] = f2bf(Ws2[(     quad * 8 + i) * 32 + cc]);
        Bw01[i] = f2bf(Ws2[(32 + quad * 8 + i) * 32 + cc]);
        Bw10[i] = f2bf(Ws2[(     quad * 8 + i) * 32 + 16 + cc]);
        Bw11[i] = f2bf(Ws2[(32 + quad * 8 + i) * 32 + 16 + cc]);
    }
    float bsq0[8], bsq1[8];
    #pragma unroll
    for (int i = 0; i < 8; ++i) {
        bsq0[i] = bs1[quad * 8 + i];
        bsq1[i] = bs1[32 + quad * 8 + i];
    }
    const float bs2c0 = bs2[cc], bs2c1 = bs2[16 + cc];
    __syncthreads();

    // ---- spatial pairwise MLP: 8 waves x 4 j's ----
    #pragma unroll 2
    for (int jj = 0; jj < 4; ++jj) {
        const int jrow = w * 4 + jj;       // wave-uniform j, 0..31
        float vj0[8], vj1[8];
        #pragma unroll
        for (int i = 0; i < 8; ++i) {
            vj0[i] = sm.s.su[jrow][quad * 8 + i] - bsq0[i];
            vj1[i] = sm.s.su[jrow][32 + quad * 8 + i] - bsq1[i];
        }
        float acc0 = 0.0f, acc1 = 0.0f;
        #pragma unroll
        for (int it = 0; it < 2; ++it) {
            const int irow = it * 16 + cc;   // A-frag row m = cc
            const float4 p0 = *(const float4*)&sm.s.su[irow][quad * 8];
            const float4 p1 = *(const float4*)&sm.s.su[irow][quad * 8 + 4];
            const float4 p2 = *(const float4*)&sm.s.su[irow][32 + quad * 8];
            const float4 p3 = *(const float4*)&sm.s.su[irow][32 + quad * 8 + 4];
            short8 A0, A1;
            A0[0] = f2bf(leakyf(p0.x - vj0[0])); A0[1] = f2bf(leakyf(p0.y - vj0[1]));
            A0[2] = f2bf(leakyf(p0.z - vj0[2])); A0[3] = f2bf(leakyf(p0.w - vj0[3]));
            A0[4] = f2bf(leakyf(p1.x - vj0[4])); A0[5] = f2bf(leakyf(p1.y - vj0[5]));
            A0[6] = f2bf(leakyf(p1.z - vj0[6])); A0[7] = f2bf(leakyf(p1.w - vj0[7]));
            A1[0] = f2bf(leakyf(p2.x - vj1[0])); A1[1] = f2bf(leakyf(p2.y - vj1[1]));
            A1[2] = f2bf(leakyf(p2.z - vj1[2])); A1[3] = f2bf(leakyf(p2.w - vj1[3]));
            A1[4] = f2bf(leakyf(p3.x - vj1[4])); A1[5] = f2bf(leakyf(p3.y - vj1[5]));
            A1[6] = f2bf(leakyf(p3.z - vj1[6])); A1[7] = f2bf(leakyf(p3.w - vj1[7]));
            const floatx4 z4 = {0.f, 0.f, 0.f, 0.f};
            const floatx4 D0 = MFMA16(A1, Bw01, MFMA16(A0, Bw00, z4));
            const floatx4 D1 = MFMA16(A1, Bw11, MFMA16(A0, Bw10, z4));
            #pragma unroll
            for (int r = 0; r < 4; ++r) {
                acc0 += leakyf(D0[r] + bs2c0);
                acc1 += leakyf(D1[r] + bs2c1);
            }
        }
        acc0 += __shfl_xor(acc0, 16, 64); acc0 += __shfl_xor(acc0, 32, 64);
        acc1 += __shfl_xor(acc1, 16, 64); acc1 += __shfl_xor(acc1, 32, 64);
        const int n = index_div[g * NGRP + jrow];
        if (quad == 0) {
            const float pv = (acc0 - sm.s.szero[cc]) * (1.0f / 31.0f);
            full_enc[n * HH + 32 + cc] = pv;
            sm.s.fe[jrow][32 + cc] = pv;
        } else if (quad == 1) {
            const float pv = (acc1 - sm.s.szero[16 + cc]) * (1.0f / 31.0f);
            full_enc[n * HH + 48 + cc] = pv;
            sm.s.fe[jrow][48 + cc] = pv;
        }
    }
    __syncthreads();

    // ---- head: x_logit = leaky(fe @ Wo1 + bo1) @ Wo2 + bo2 ----
    {
        const int veh = tid >> 4;          // 0..31
        const int p   = tid & 15;          // hidden dim
        float a = bo1[p];
        #pragma unroll
        for (int k = 0; k < HH; ++k)
            a = fmaf(sm.s.fe[veh][k], sm.s.swo1[k * 16 + p], a);
        a = leakyf(a);
        float l0 = a * Wo2[p * 3 + 0];
        float l1 = a * Wo2[p * 3 + 1];
        float l2 = a * Wo2[p * 3 + 2];
        #pragma unroll
        for (int off = 1; off < 16; off <<= 1) {
            l0 += __shfl_xor(l0, off, 64);
            l1 += __shfl_xor(l1, off, 64);
            l2 += __shfl_xor(l2, off, 64);
        }
        if (p == 0) {
            const int n = index_div[g * NGRP + veh];
            out[n * 3 + 0] = l0 + bo2[0];
            out[n * 3 + 1] = l1 + bo2[1];
            out[n * 3 + 2] = l2 + bo2[2];
        }
    }
}

// ---------------------------------------------------------------------------
extern "C" void kernel_launch(void* const* d_in, const int* in_sizes, int n_in,
                              void* d_out, int out_size, void* d_ws, size_t ws_size,
                              hipStream_t stream) {
    const float* scene     = (const float*)d_in[0];
    const int*   index_div = (const int*)d_in[4];
    const float* W_emb = (const float*)d_in[5];
    const float* b_emb = (const float*)d_in[6];
    const float* Wih_f = (const float*)d_in[7];
    const float* Whh_f = (const float*)d_in[8];
    const float* bih_f = (const float*)d_in[9];
    const float* bhh_f = (const float*)d_in[10];
    const float* Wih_b = (const float*)d_in[11];
    const float* Whh_b = (const float*)d_in[12];
    const float* bih_b = (const float*)d_in[13];
    const float* bhh_b = (const float*)d_in[14];
    const float* Wm  = (const float*)d_in[15];
    const float* bm  = (const float*)d_in[16];
    const float* Ws1 = (const float*)d_in[17];
    const float* bs1 = (const float*)d_in[18];
    const float* Ws2 = (const float*)d_in[19];
    const float* bs2 = (const float*)d_in[20];
    const float* Wo1 = (const float*)d_in[21];
    const float* bo1 = (const float*)d_in[22];
    const float* Wo2 = (const float*)d_in[23];
    const float* bo2 = (const float*)d_in[24];

    const int N = in_sizes[0] / (2 * TT);   // 32768
    const int G = in_sizes[4] / NGRP;       // 1024

    float* out      = (float*)d_out;
    float* full_enc = out + (size_t)N * CC;

    fused_kernel<<<dim3(G), dim3(512), 0, stream>>>(
        scene, index_div, W_emb, b_emb, Wih_f, Whh_f, bih_f, bhh_f,
        Wih_b, Whh_b, bih_b, bhh_b, Wm, bm, Ws1, bs1, Ws2, bs2,
        Wo1, bo1, Wo2, bo2, full_enc, out);
}

// Round 5
// 216.475 us; speedup vs baseline: 1.0654x; 1.0654x over previous
//
#include <hip/hip_runtime.h>
#include <hip/hip_bf16.h>

#define TT 16      // in_length
#define EE 32      // embedding size
#define HH 64      // encoder size
#define NGRP 32    // vehicles per group
#define CC 3       // classes

typedef __attribute__((ext_vector_type(8))) short short8;
typedef __attribute__((ext_vector_type(4))) float floatx4;

#define MFMA16(a, b, c) __builtin_amdgcn_mfma_f32_16x16x32_bf16((a), (b), (c), 0, 0, 0)

#define RLN2 1.4426950408889634f   // 1/ln2

__device__ __forceinline__ float leakyf(float x) { return fmaxf(x, 0.1f * x); }
__device__ __forceinline__ short f2bf(float x) {   // fp32 -> bf16 RNE (one-time weights)
    unsigned u = __float_as_uint(x);
    return (short)((u + 0x7FFFu + ((u >> 16) & 1u)) >> 16);
}
__device__ __forceinline__ short f2bf_h(float x) { // fp32 -> bf16 round-half-up (per-step)
    return (short)((__float_as_uint(x) + 0x8000u) >> 16);
}
__device__ __forceinline__ float bf2f(short s) {
    return __uint_as_float(((unsigned)(unsigned short)s) << 16);
}
__device__ __forceinline__ short8 ld8bfs(const float* __restrict__ p, float s) {
    const float4 a = *(const float4*)p;
    const float4 b = *(const float4*)(p + 4);
    short8 v;
    v[0] = f2bf(a.x * s); v[1] = f2bf(a.y * s); v[2] = f2bf(a.z * s); v[3] = f2bf(a.w * s);
    v[4] = f2bf(b.x * s); v[5] = f2bf(b.y * s); v[6] = f2bf(b.z * s); v[7] = f2bf(b.w * s);
    return v;
}

// ---------------------------------------------------------------------------
// ONE fused kernel. Block g = scene group g. 512 threads = 8 waves.
//
// R12: (512,6) + GRU loop UNROLL 1. Evidence ledger:
//   * R2: LDS 53760->40960, dur flat, occ 38% -> LDS never the cap.
//   * R3: VALU -21% (busy 69->55), dur flat -> not VALU-throughput-bound.
//   * R4: (512,6): occupancy 38->53% (3 blocks DID become resident) but
//     FETCH 74MB/WRITE 180MB = spills -> dur 141. Overshoot is small.
//   Live-set hand count for the GRU loop: 9 B-frags(36) + h_reg(8) + vb(4)
//   + Ah/Axx(12) + 4 acc(16) + addr(~8) = 84 ~= the 85-reg budget of
//   (512,6). The '#pragma unroll 2' on the step loop keeps TWO steps'
//   transients live -> peak >85 -> spill. This round: unroll 1, nothing else.
// Sentinels: FETCH >~10MB => live set genuinely >85 (next: stream n-gate
//   B-frags from L2, -12 regs, or split spatial into own kernel).
//   Spill-free but dur ~107 => occupancy exhausted; attack gate-math trans.
//
// LDS layout (40960 B): Hf single-buffered (2 barriers/step); scene staged
// transiently in Hf bytes pre-loop, re-gathered from L2 post-loop.
// Phase 1 (GRU): waves 0-3 fwd, 4-7 bwd; wave wd owns gate cols [16wd,16wd+16).
//   B-frags pre-scaled by -1/ln2 (r,z) / 2/ln2 (n); biases added as scalars
//   after the MFMA. sigma(x)=rcp(1+exp2(-x/ln2)), tanh(t)=1-2*rcp(exp2(2t/ln2)+1).
//   Hf write slot permuted (slot = qa*16 + r*4 + quad); reads use rlane.
// Phase 2 (spatial MFMA) + Phase 3 (head): R6 structure; spatial arrays
//   overlay dead Xall in a union; Hf region preserved for epilogue.
// ---------------------------------------------------------------------------
__global__ __launch_bounds__(512, 6) void fused_kernel(
    const float* __restrict__ scene, const int* __restrict__ index_div,
    const float* __restrict__ W_emb, const float* __restrict__ b_emb,
    const float* __restrict__ Wih_f, const float* __restrict__ Whh_f,
    const float* __restrict__ bih_f, const float* __restrict__ bhh_f,
    const float* __restrict__ Wih_b, const float* __restrict__ Whh_b,
    const float* __restrict__ bih_b, const float* __restrict__ bhh_b,
    const float* __restrict__ Wm, const float* __restrict__ bm,
    const float* __restrict__ Ws1, const float* __restrict__ bs1,
    const float* __restrict__ Ws2, const float* __restrict__ bs2,
    const float* __restrict__ Wo1, const float* __restrict__ bo1,
    const float* __restrict__ Wo2, const float* __restrict__ bo2,
    float* __restrict__ full_enc, float* __restrict__ out)
{
    __shared__ __align__(16) union SmemU {
        struct {                                     // GRU phase: 40960 B exactly
            short Xall[16 * 2 * 64 * 8];             // [t][mt][lane][8]      32768 B
            short Hf[2 * 2 * 2 * 64 * 8];            // [dir][ks][mt][slot][8] 8192 B (single buf)
        } g;
        struct {                                     // spatial/head phase (25856 B < 32768 B)
            float su[NGRP][68];                      //  8704 B
            float fe[NGRP][68];                      //  8704 B
            float swo1[1024];                        //  4096 B
            float szero[32];                         //   128 B
            float sscene2[32][33];                   //  4224 B  (re-gathered scene, [c][veh])
        } s;
    } sm;

    const int g    = blockIdx.x;
    const int tid  = threadIdx.x;
    const int lane = tid & 63;
    const int w    = __builtin_amdgcn_readfirstlane(tid >> 6);  // 0..7
    const int dir  = w >> 2;
    const int wd   = w & 3;
    const int cc   = lane & 15;
    const int quad = lane >> 4;
    const int j    = wd * 16 + cc;            // gate column
    const int ks_w = j >> 5;
    const int qa_w = (j >> 3) & 3;
    const int ii_w = j & 7;
    // permuted reader lane: slot(Lq, m) = Lq*16 + (m&3)*4 + (m>>2)
    const int rlane = (lane & 48) | ((lane & 3) << 2) | ((lane >> 2) & 3);

    // ---- stage gathered scene rows into the (not-yet-live) Hf bytes as
    //      float sc0[32][33] (4224 B <= 8192 B) ----
    {
        float* sc0 = (float*)sm.g.Hf;
        #pragma unroll
        for (int rep = 0; rep < 2; ++rep) {
            const int idx = tid + rep * 512;
            const int v = idx >> 5, c = idx & 31;
            const int n = index_div[g * NGRP + v];
            sc0[c * 33 + v] = scene[n * 32 + c];
        }
    }

    // ---- per-wave GRU B-frags, pre-scaled; biases stay SCALAR ----
    const float* Wih = dir ? Wih_b : Wih_f;
    const float* Whh = dir ? Whh_b : Whh_f;
    const float* bih = dir ? bih_b : bih_f;
    const float* bhh = dir ? bhh_b : bhh_f;
    const int k0 = quad * 8;
    const float SRZ = -RLN2, SN = 2.0f * RLN2;
    const short8 Br0  = ld8bfs(Whh + (j      ) * 64 + k0,      SRZ);
    const short8 Br1  = ld8bfs(Whh + (j      ) * 64 + 32 + k0, SRZ);
    const short8 Br2  = ld8bfs(Wih + (j      ) * 32 + k0,      SRZ);
    const short8 Bz0  = ld8bfs(Whh + (j +  64) * 64 + k0,      SRZ);
    const short8 Bz1  = ld8bfs(Whh + (j +  64) * 64 + 32 + k0, SRZ);
    const short8 Bz2  = ld8bfs(Wih + (j +  64) * 32 + k0,      SRZ);
    const short8 Bhn0 = ld8bfs(Whh + (j + 128) * 64 + k0,      SN);
    const short8 Bhn1 = ld8bfs(Whh + (j + 128) * 64 + 32 + k0, SN);
    const short8 Bxn  = ld8bfs(Wih + (j + 128) * 32 + k0,      SN);
    const float vb_r  = SRZ * (bih[j] + bhh[j]);
    const float vb_z  = SRZ * (bih[j + 64] + bhh[j + 64]);
    const float vb_xn = SN * bih[j + 128];
    const float vb_hn = SN * bhh[j + 128];

    __syncthreads();   // sc0 ready

    // ---- emb for ALL t (512 threads = 16 t x 32 veh); reads sc0 (in Hf
    //      bytes), writes Xall only. Barrier, THEN zero Hf. ----
    {
        const float* sc0 = (const float*)sm.g.Hf;
        const int t   = tid >> 5;
        const int veh = tid & 31;
        const float xs = sc0[t * 33 + veh];
        const float ys = sc0[(16 + t) * 33 + veh];
        const int mt = veh >> 4;
        const int m  = veh & 15;
        #pragma unroll
        for (int q = 0; q < 4; ++q) {
            short8 v;
            #pragma unroll
            for (int i2 = 0; i2 < 8; ++i2) {
                const int e = q * 8 + i2;
                v[i2] = f2bf(leakyf(fmaf(xs, W_emb[e], fmaf(ys, W_emb[EE + e], b_emb[e]))));
            }
            *(short8*)&sm.g.Xall[(((t * 2 + mt) * 64) + q * 16 + m) * 8] = v;
        }
    }
    __syncthreads();   // all sc0 reads consumed -> Hf bytes reusable
    {
        const short8 z8 = {0, 0, 0, 0, 0, 0, 0, 0};
        *(short8*)&sm.g.Hf[tid * 8] = z8;     // zero all 4096 shorts (both dirs)
    }

    float h_reg[8];
    #pragma unroll
    for (int i = 0; i < 8; ++i) h_reg[i] = 0.0f;

    const int hf_dir = dir * 2048;                 // shorts (dir stride, single buf)
    __syncthreads();   // Hf zeroed

    // ---- GRU main loop: single-buffered Hf, TWO barriers per step.
    //      UNROLL 1: under the (512,6) 85-reg budget, unroll-2's doubled
    //      transients are exactly the spill margin (R4 post-mortem). ----
    #pragma unroll 1
    for (int s = 0; s < TT; ++s) {
        const int t  = dir ? (TT - 1 - s) : s;
        const short* HfD = &sm.g.Hf[hf_dir];
        #pragma unroll
        for (int mt = 0; mt < 2; ++mt) {
            const short8 Ah0 = *(const short8*)&HfD[((0 * 2 + mt) * 64 + rlane) * 8];
            const short8 Ah1 = *(const short8*)&HfD[((1 * 2 + mt) * 64 + rlane) * 8];
            const short8 Axx = *(const short8*)&sm.g.Xall[((t * 2 + mt) * 64 + lane) * 8];
            const floatx4 z4 = {0.f, 0.f, 0.f, 0.f};
            const floatx4 ar  = MFMA16(Axx, Br2, MFMA16(Ah1, Br1, MFMA16(Ah0, Br0, z4)));
            const floatx4 az  = MFMA16(Axx, Bz2, MFMA16(Ah1, Bz1, MFMA16(Ah0, Bz0, z4)));
            const floatx4 ahn = MFMA16(Ah1, Bhn1, MFMA16(Ah0, Bhn0, z4));
            const floatx4 axn = MFMA16(Axx, Bxn, z4);
            #pragma unroll
            for (int r = 0; r < 4; ++r) {
                // ar = -pre_r/ln2 (pre-scaled); rr = sigmoid(pre_r)
                const float rr = __builtin_amdgcn_rcpf(1.0f + __builtin_amdgcn_exp2f(ar[r] + vb_r));
                const float zz = __builtin_amdgcn_rcpf(1.0f + __builtin_amdgcn_exp2f(az[r] + vb_z));
                // y = 2*(xn + rr*hn)/ln2 ; ng = tanh(xn + rr*hn)
                const float y  = fmaf(rr, ahn[r] + vb_hn, axn[r] + vb_xn);
                const float ng = fmaf(-2.0f,
                                      __builtin_amdgcn_rcpf(__builtin_amdgcn_exp2f(y) + 1.0f),
                                      1.0f);
                const float h0 = h_reg[mt * 4 + r];
                h_reg[mt * 4 + r] = fmaf(zz, h0 - ng, ng);  // (1-z)*ng + z*h
            }
        }
        __syncthreads();   // all waves' Hf reads complete -> in-place write safe
        short* HfW = &sm.g.Hf[hf_dir];
        #pragma unroll
        for (int mt = 0; mt < 2; ++mt) {
            #pragma unroll
            for (int r = 0; r < 4; ++r) {
                const int slot = qa_w * 16 + r * 4 + quad;   // perm of qa*16 + m
                HfW[((ks_w * 2 + mt) * 64 + slot) * 8 + ii_w] = f2bf_h(h_reg[mt * 4 + r]);
            }
        }
        __syncthreads();   // writes visible for next step
    }
    // Final h in Hf[dir]. Xall dead from here.

    // ---- re-gather scene into spatial union region (L2-hot; HBM idle) ----
    #pragma unroll
    for (int rep = 0; rep < 2; ++rep) {
        const int idx = tid + rep * 512;
        const int v = idx >> 5, c = idx & 31;
        const int n = index_div[g * NGRP + v];
        sm.s.sscene2[c][v] = scene[n * 32 + c];
    }
    __syncthreads();   // sscene2 ready

    // ---- Phase 2 prep: waves 0-3 seq_enc epilogue; waves 4-7 su/swo1/szero ----
    if (w < 4) {
        const int nt   = w >> 1;
        const int mt_e = w & 1;
        const int n_col = nt * 16 + cc;
        short8 Bm0, Bm1;
        #pragma unroll
        for (int i = 0; i < 8; ++i) {
            Bm0[i] = f2bf(Wm[(     quad * 8 + i) * 32 + n_col]);
            Bm1[i] = f2bf(Wm[(32 + quad * 8 + i) * 32 + n_col]);
        }
        short8 A0, A1;
        #pragma unroll
        for (int ks = 0; ks < 2; ++ks) {
            const short8 F = *(const short8*)&sm.g.Hf[0    + ((ks * 2 + mt_e) * 64 + rlane) * 8];
            const short8 B = *(const short8*)&sm.g.Hf[2048 + ((ks * 2 + mt_e) * 64 + rlane) * 8];
            #pragma unroll
            for (int i = 0; i < 8; ++i) {
                const short v = f2bf(0.5f * (bf2f(F[i]) + bf2f(B[i])));
                if (ks == 0) A0[i] = v; else A1[i] = v;
            }
        }
        const floatx4 z4 = {0.f, 0.f, 0.f, 0.f};
        const floatx4 acc = MFMA16(A1, Bm1, MFMA16(A0, Bm0, z4));
        const float bmn = bm[n_col];
        #pragma unroll
        for (int r = 0; r < 4; ++r) {
            const int veh = mt_e * 16 + quad * 4 + r;
            const float sv = leakyf(acc[r] + bmn);
            const int n = index_div[g * NGRP + veh];
            full_enc[n * HH + n_col] = sv;
            sm.s.fe[veh][n_col] = sv;     // fe region does not overlap Hf
        }
    } else {
        const int l  = tid & 255;
        const int v  = l >> 3;
        const int d0 = (l & 7) * 8;
        float acc[8];
        #pragma unroll
        for (int i = 0; i < 8; ++i) acc[i] = 0.0f;
        #pragma unroll
        for (int e = 0; e < EE; ++e) {
            const float f = sm.s.sscene2[e][v];
            const float4 w0 = *(const float4*)&Ws1[e * 64 + d0];
            const float4 w1 = *(const float4*)&Ws1[e * 64 + d0 + 4];
            acc[0] = fmaf(f, w0.x, acc[0]); acc[1] = fmaf(f, w0.y, acc[1]);
            acc[2] = fmaf(f, w0.z, acc[2]); acc[3] = fmaf(f, w0.w, acc[3]);
            acc[4] = fmaf(f, w1.x, acc[4]); acc[5] = fmaf(f, w1.y, acc[5]);
            acc[6] = fmaf(f, w1.z, acc[6]); acc[7] = fmaf(f, w1.w, acc[7]);
        }
        #pragma unroll
        for (int i = 0; i < 8; ++i) sm.s.su[v][d0 + i] = acc[i];
        *(float4*)&sm.s.swo1[l * 4] = *(const float4*)&Wo1[l * 4];
        if (l < 32) {
            float zs = bs2[l];
            #pragma unroll
            for (int d = 0; d < HH; ++d) zs = fmaf(leakyf(bs1[d]), Ws2[d * 32 + l], zs);
            sm.s.szero[l] = leakyf(zs);
        }
    }

    // ---- spatial B-frags (all 8 waves) ----
    short8 Bw00, Bw01, Bw10, Bw11;
    #pragma unroll
    for (int i = 0; i < 8; ++i) {
        Bw00[i] = f2bf(Ws2[(     quad * 8 + i) * 32 + cc]);
        Bw01[i] = f2bf(Ws2[(32 + quad * 8 + i) * 32 + cc]);
        Bw10[i] = f2bf(Ws2[(     quad * 8 + i) * 32 + 16 + cc]);
        Bw11[i] = f2bf(Ws2[(32 + quad * 8 + i) * 32 + 16 + cc]);
    }
    float bsq0[8], bsq1[8];
    #pragma unroll
    for (int i = 0; i < 8; ++i) {
        bsq0[i] = bs1[quad * 8 + i];
        bsq1[i] = bs1[32 + quad * 8 + i];
    }
    const float bs2c0 = bs2[cc], bs2c1 = bs2[16 + cc];
    __syncthreads();

    // ---- spatial pairwise MLP: 8 waves x 4 j's ----
    #pragma unroll 2
    for (int jj = 0; jj < 4; ++jj) {
        const int jrow = w * 4 + jj;       // wave-uniform j, 0..31
        float vj0[8], vj1[8];
        #pragma unroll
        for (int i = 0; i < 8; ++i) {
            vj0[i] = sm.s.su[jrow][quad * 8 + i] - bsq0[i];
            vj1[i] = sm.s.su[jrow][32 + quad * 8 + i] - bsq1[i];
        }
        float acc0 = 0.0f, acc1 = 0.0f;
        #pragma unroll
        for (int it = 0; it < 2; ++it) {
            const int irow = it * 16 + cc;   // A-frag row m = cc
            const float4 p0 = *(const float4*)&sm.s.su[irow][quad * 8];
            const float4 p1 = *(const float4*)&sm.s.su[irow][quad * 8 + 4];
            const float4 p2 = *(const float4*)&sm.s.su[irow][32 + quad * 8];
            const float4 p3 = *(const float4*)&sm.s.su[irow][32 + quad * 8 + 4];
            short8 A0, A1;
            A0[0] = f2bf(leakyf(p0.x - vj0[0])); A0[1] = f2bf(leakyf(p0.y - vj0[1]));
            A0[2] = f2bf(leakyf(p0.z - vj0[2])); A0[3] = f2bf(leakyf(p0.w - vj0[3]));
            A0[4] = f2bf(leakyf(p1.x - vj0[4])); A0[5] = f2bf(leakyf(p1.y - vj0[5]));
            A0[6] = f2bf(leakyf(p1.z - vj0[6])); A0[7] = f2bf(leakyf(p1.w - vj0[7]));
            A1[0] = f2bf(leakyf(p2.x - vj1[0])); A1[1] = f2bf(leakyf(p2.y - vj1[1]));
            A1[2] = f2bf(leakyf(p2.z - vj1[2])); A1[3] = f2bf(leakyf(p2.w - vj1[3]));
            A1[4] = f2bf(leakyf(p3.x - vj1[4])); A1[5] = f2bf(leakyf(p3.y - vj1[5]));
            A1[6] = f2bf(leakyf(p3.z - vj1[6])); A1[7] = f2bf(leakyf(p3.w - vj1[7]));
            const floatx4 z4 = {0.f, 0.f, 0.f, 0.f};
            const floatx4 D0 = MFMA16(A1, Bw01, MFMA16(A0, Bw00, z4));
            const floatx4 D1 = MFMA16(A1, Bw11, MFMA16(A0, Bw10, z4));
            #pragma unroll
            for (int r = 0; r < 4; ++r) {
                acc0 += leakyf(D0[r] + bs2c0);
                acc1 += leakyf(D1[r] + bs2c1);
            }
        }
        acc0 += __shfl_xor(acc0, 16, 64); acc0 += __shfl_xor(acc0, 32, 64);
        acc1 += __shfl_xor(acc1, 16, 64); acc1 += __shfl_xor(acc1, 32, 64);
        const int n = index_div[g * NGRP + jrow];
        if (quad == 0) {
            const float pv = (acc0 - sm.s.szero[cc]) * (1.0f / 31.0f);
            full_enc[n * HH + 32 + cc] = pv;
            sm.s.fe[jrow][32 + cc] = pv;
        } else if (quad == 1) {
            const float pv = (acc1 - sm.s.szero[16 + cc]) * (1.0f / 31.0f);
            full_enc[n * HH + 48 + cc] = pv;
            sm.s.fe[jrow][48 + cc] = pv;
        }
    }
    __syncthreads();

    // ---- head: x_logit = leaky(fe @ Wo1 + bo1) @ Wo2 + bo2 ----
    {
        const int veh = tid >> 4;          // 0..31
        const int p   = tid & 15;          // hidden dim
        float a = bo1[p];
        #pragma unroll
        for (int k = 0; k < HH; ++k)
            a = fmaf(sm.s.fe[veh][k], sm.s.swo1[k * 16 + p], a);
        a = leakyf(a);
        float l0 = a * Wo2[p * 3 + 0];
        float l1 = a * Wo2[p * 3 + 1];
        float l2 = a * Wo2[p * 3 + 2];
        #pragma unroll
        for (int off = 1; off < 16; off <<= 1) {
            l0 += __shfl_xor(l0, off, 64);
            l1 += __shfl_xor(l1, off, 64);
            l2 += __shfl_xor(l2, off, 64);
        }
        if (p == 0) {
            const int n = index_div[g * NGRP + veh];
            out[n * 3 + 0] = l0 + bo2[0];
            out[n * 3 + 1] = l1 + bo2[1];
            out[n * 3 + 2] = l2 + bo2[2];
        }
    }
}

// ---------------------------------------------------------------------------
extern "C" void kernel_launch(void* const* d_in, const int* in_sizes, int n_in,
                              void* d_out, int out_size, void* d_ws, size_t ws_size,
                              hipStream_t stream) {
    const float* scene     = (const float*)d_in[0];
    const int*   index_div = (const int*)d_in[4];
    const float* W_emb = (const float*)d_in[5];
    const float* b_emb = (const float*)d_in[6];
    const float* Wih_f = (const float*)d_in[7];
    const float* Whh_f = (const float*)d_in[8];
    const float* bih_f = (const float*)d_in[9];
    const float* bhh_f = (const float*)d_in[10];
    const float* Wih_b = (const float*)d_in[11];
    const float* Whh_b = (const float*)d_in[12];
    const float* bih_b = (const float*)d_in[13];
    const float* bhh_b = (const float*)d_in[14];
    const float* Wm  = (const float*)d_in[15];
    const float* bm  = (const float*)d_in[16];
    const float* Ws1 = (const float*)d_in[17];
    const float* bs1 = (const float*)d_in[18];
    const float* Ws2 = (const float*)d_in[19];
    const float* bs2 = (const float*)d_in[20];
    const float* Wo1 = (const float*)d_in[21];
    const float* bo1 = (const float*)d_in[22];
    const float* Wo2 = (const float*)d_in[23];
    const float* bo2 = (const float*)d_in[24];

    const int N = in_sizes[0] / (2 * TT);   // 32768
    const int G = in_sizes[4] / NGRP;       // 1024

    float* out      = (float*)d_out;
    float* full_enc = out + (size_t)N * CC;

    fused_kernel<<<dim3(G), dim3(512), 0, stream>>>(
        scene, index_div, W_emb, b_emb, Wih_f, Whh_f, bih_f, bhh_f,
        Wih_b, Whh_b, bih_b, bhh_b, Wm, bm, Ws1, bs1, Ws2, bs2,
        Wo1, bo1, Wo2, bo2, full_enc, out);
}

// Round 6
// 213.802 us; speedup vs baseline: 1.0787x; 1.0125x over previous
//
#include <hip/hip_runtime.h>
#include <hip/hip_bf16.h>

#define TT 16      // in_length
#define EE 32      // embedding size
#define HH 64      // encoder size
#define NGRP 32    // vehicles per group
#define CC 3       // classes

typedef __attribute__((ext_vector_type(8))) short short8;
typedef __attribute__((ext_vector_type(4))) float floatx4;

#define MFMA16(a, b, c) __builtin_amdgcn_mfma_f32_16x16x32_bf16((a), (b), (c), 0, 0, 0)

#define RLN2 1.4426950408889634f   // 1/ln2

__device__ __forceinline__ float leakyf(float x) { return fmaxf(x, 0.1f * x); }
__device__ __forceinline__ short f2bf(float x) {   // fp32 -> bf16 RNE (one-time weights)
    unsigned u = __float_as_uint(x);
    return (short)((u + 0x7FFFu + ((u >> 16) & 1u)) >> 16);
}
__device__ __forceinline__ short f2bf_h(float x) { // fp32 -> bf16 round-half-up (per-step)
    return (short)((__float_as_uint(x) + 0x8000u) >> 16);
}
__device__ __forceinline__ float bf2f(short s) {
    return __uint_as_float(((unsigned)(unsigned short)s) << 16);
}
__device__ __forceinline__ short8 ld8bfs(const float* __restrict__ p, float s) {
    const float4 a = *(const float4*)p;
    const float4 b = *(const float4*)(p + 4);
    short8 v;
    v[0] = f2bf(a.x * s); v[1] = f2bf(a.y * s); v[2] = f2bf(a.z * s); v[3] = f2bf(a.w * s);
    v[4] = f2bf(b.x * s); v[5] = f2bf(b.y * s); v[6] = f2bf(b.z * s); v[7] = f2bf(b.w * s);
    return v;
}

// ---------------------------------------------------------------------------
// ONE fused kernel. Block g = scene group g. 512 threads = 8 waves.
//
// R13: gate-SERIALIZED GRU step to fit the (512,6) 85-reg budget.
// Evidence ledger:
//   * R2: LDS diet -> 4-block capable; dur flat; occ 38% -> LDS not the cap.
//   * R3: VALU ops -21%; dur flat -> not VALU-throughput-bound.
//   * R4: (512,6) unroll2: occ 53% BUT spills (74MB fetch) -> dur 141.
//   * R5: unroll1: spills shrink (44MB) -> dur 128. Monotone: each live-set
//     cut shrinks spill+time. Still ~6-12 regs over budget.
//   Peak liveness culprit: all 4 MFMA accumulators (ar/az/ahn/axn = 16 regs)
//   live at once on top of A(12)+B(36)+h(8)+vb(4)+addr.
// This round: serialize gates within the step -- r-gate MFMAs -> rr[] (ar
// dies); n-gate -> ng[] (ahn/axn die); z-gate -> h update (az dies). Peak
// acc 16 -> ~8-12; total ~72-76 < 85. sched_barrier(0) fences keep the
// scheduler from re-hoisting the independent chains (that hoisting IS the
// register bloat). Arithmetic order per element unchanged -> bit-identical.
// Sentinels: FETCH >~20MB => live set >85 regardless -> abandon (512,6).
//   Spill-free but dur ~107 => occupancy not the cure -> restructure next.
//
// LDS layout (40960 B): Hf single-buffered (2 barriers/step); scene staged
// transiently in Hf bytes pre-loop, re-gathered from L2 post-loop.
// Phase 1 (GRU): waves 0-3 fwd, 4-7 bwd; wave wd owns gate cols [16wd,16wd+16).
//   B-frags pre-scaled by -1/ln2 (r,z) / 2/ln2 (n); biases added as scalars
//   after the MFMA. sigma(x)=rcp(1+exp2(-x/ln2)), tanh(t)=1-2*rcp(exp2(2t/ln2)+1).
//   Hf write slot permuted (slot = qa*16 + r*4 + quad); reads use rlane.
// Phase 2 (spatial MFMA) + Phase 3 (head): R6 structure; spatial arrays
//   overlay dead Xall in a union; Hf region preserved for epilogue.
// ---------------------------------------------------------------------------
__global__ __launch_bounds__(512, 6) void fused_kernel(
    const float* __restrict__ scene, const int* __restrict__ index_div,
    const float* __restrict__ W_emb, const float* __restrict__ b_emb,
    const float* __restrict__ Wih_f, const float* __restrict__ Whh_f,
    const float* __restrict__ bih_f, const float* __restrict__ bhh_f,
    const float* __restrict__ Wih_b, const float* __restrict__ Whh_b,
    const float* __restrict__ bih_b, const float* __restrict__ bhh_b,
    const float* __restrict__ Wm, const float* __restrict__ bm,
    const float* __restrict__ Ws1, const float* __restrict__ bs1,
    const float* __restrict__ Ws2, const float* __restrict__ bs2,
    const float* __restrict__ Wo1, const float* __restrict__ bo1,
    const float* __restrict__ Wo2, const float* __restrict__ bo2,
    float* __restrict__ full_enc, float* __restrict__ out)
{
    __shared__ __align__(16) union SmemU {
        struct {                                     // GRU phase: 40960 B exactly
            short Xall[16 * 2 * 64 * 8];             // [t][mt][lane][8]      32768 B
            short Hf[2 * 2 * 2 * 64 * 8];            // [dir][ks][mt][slot][8] 8192 B (single buf)
        } g;
        struct {                                     // spatial/head phase (25856 B < 32768 B)
            float su[NGRP][68];                      //  8704 B
            float fe[NGRP][68];                      //  8704 B
            float swo1[1024];                        //  4096 B
            float szero[32];                         //   128 B
            float sscene2[32][33];                   //  4224 B  (re-gathered scene, [c][veh])
        } s;
    } sm;

    const int g    = blockIdx.x;
    const int tid  = threadIdx.x;
    const int lane = tid & 63;
    const int w    = __builtin_amdgcn_readfirstlane(tid >> 6);  // 0..7
    const int dir  = w >> 2;
    const int wd   = w & 3;
    const int cc   = lane & 15;
    const int quad = lane >> 4;
    const int j    = wd * 16 + cc;            // gate column
    const int ks_w = j >> 5;
    const int qa_w = (j >> 3) & 3;
    const int ii_w = j & 7;
    // permuted reader lane: slot(Lq, m) = Lq*16 + (m&3)*4 + (m>>2)
    const int rlane = (lane & 48) | ((lane & 3) << 2) | ((lane >> 2) & 3);

    // ---- stage gathered scene rows into the (not-yet-live) Hf bytes as
    //      float sc0[32][33] (4224 B <= 8192 B) ----
    {
        float* sc0 = (float*)sm.g.Hf;
        #pragma unroll
        for (int rep = 0; rep < 2; ++rep) {
            const int idx = tid + rep * 512;
            const int v = idx >> 5, c = idx & 31;
            const int n = index_div[g * NGRP + v];
            sc0[c * 33 + v] = scene[n * 32 + c];
        }
    }

    // ---- per-wave GRU B-frags, pre-scaled; biases stay SCALAR ----
    const float* Wih = dir ? Wih_b : Wih_f;
    const float* Whh = dir ? Whh_b : Whh_f;
    const float* bih = dir ? bih_b : bih_f;
    const float* bhh = dir ? bhh_b : bhh_f;
    const int k0 = quad * 8;
    const float SRZ = -RLN2, SN = 2.0f * RLN2;
    const short8 Br0  = ld8bfs(Whh + (j      ) * 64 + k0,      SRZ);
    const short8 Br1  = ld8bfs(Whh + (j      ) * 64 + 32 + k0, SRZ);
    const short8 Br2  = ld8bfs(Wih + (j      ) * 32 + k0,      SRZ);
    const short8 Bz0  = ld8bfs(Whh + (j +  64) * 64 + k0,      SRZ);
    const short8 Bz1  = ld8bfs(Whh + (j +  64) * 64 + 32 + k0, SRZ);
    const short8 Bz2  = ld8bfs(Wih + (j +  64) * 32 + k0,      SRZ);
    const short8 Bhn0 = ld8bfs(Whh + (j + 128) * 64 + k0,      SN);
    const short8 Bhn1 = ld8bfs(Whh + (j + 128) * 64 + 32 + k0, SN);
    const short8 Bxn  = ld8bfs(Wih + (j + 128) * 32 + k0,      SN);
    const float vb_r  = SRZ * (bih[j] + bhh[j]);
    const float vb_z  = SRZ * (bih[j + 64] + bhh[j + 64]);
    const float vb_xn = SN * bih[j + 128];
    const float vb_hn = SN * bhh[j + 128];

    __syncthreads();   // sc0 ready

    // ---- emb for ALL t (512 threads = 16 t x 32 veh); reads sc0 (in Hf
    //      bytes), writes Xall only. Barrier, THEN zero Hf. ----
    {
        const float* sc0 = (const float*)sm.g.Hf;
        const int t   = tid >> 5;
        const int veh = tid & 31;
        const float xs = sc0[t * 33 + veh];
        const float ys = sc0[(16 + t) * 33 + veh];
        const int mt = veh >> 4;
        const int m  = veh & 15;
        #pragma unroll
        for (int q = 0; q < 4; ++q) {
            short8 v;
            #pragma unroll
            for (int i2 = 0; i2 < 8; ++i2) {
                const int e = q * 8 + i2;
                v[i2] = f2bf(leakyf(fmaf(xs, W_emb[e], fmaf(ys, W_emb[EE + e], b_emb[e]))));
            }
            *(short8*)&sm.g.Xall[(((t * 2 + mt) * 64) + q * 16 + m) * 8] = v;
        }
    }
    __syncthreads();   // all sc0 reads consumed -> Hf bytes reusable
    {
        const short8 z8 = {0, 0, 0, 0, 0, 0, 0, 0};
        *(short8*)&sm.g.Hf[tid * 8] = z8;     // zero all 4096 shorts (both dirs)
    }

    float h_reg[8];
    #pragma unroll
    for (int i = 0; i < 8; ++i) h_reg[i] = 0.0f;

    const int hf_dir = dir * 2048;                 // shorts (dir stride, single buf)
    __syncthreads();   // Hf zeroed

    // ---- GRU main loop: single-buffered Hf, TWO barriers per step.
    //      Gate-serialized: r -> n -> z so only ~1-2 MFMA accumulators are
    //      live at once (fits the 85-reg budget of (512,6)). sched_barrier
    //      fences stop the scheduler from re-hoisting the chains. ----
    #pragma unroll 1
    for (int s = 0; s < TT; ++s) {
        const int t  = dir ? (TT - 1 - s) : s;
        const short* HfD = &sm.g.Hf[hf_dir];
        #pragma unroll
        for (int mt = 0; mt < 2; ++mt) {
            const short8 Ah0 = *(const short8*)&HfD[((0 * 2 + mt) * 64 + rlane) * 8];
            const short8 Ah1 = *(const short8*)&HfD[((1 * 2 + mt) * 64 + rlane) * 8];
            const short8 Axx = *(const short8*)&sm.g.Xall[((t * 2 + mt) * 64 + lane) * 8];
            const floatx4 z4 = {0.f, 0.f, 0.f, 0.f};

            // --- r-gate: MFMA chain, consume into rr[], ar dies ---
            const floatx4 ar = MFMA16(Axx, Br2, MFMA16(Ah1, Br1, MFMA16(Ah0, Br0, z4)));
            float rr[4];
            #pragma unroll
            for (int r = 0; r < 4; ++r)
                rr[r] = __builtin_amdgcn_rcpf(1.0f + __builtin_amdgcn_exp2f(ar[r] + vb_r));
            __builtin_amdgcn_sched_barrier(0);

            // --- n-gate: MFMA chains, consume into ng[], ahn/axn die ---
            const floatx4 ahn = MFMA16(Ah1, Bhn1, MFMA16(Ah0, Bhn0, z4));
            const floatx4 axn = MFMA16(Axx, Bxn, z4);
            float ng[4];
            #pragma unroll
            for (int r = 0; r < 4; ++r) {
                const float y = fmaf(rr[r], ahn[r] + vb_hn, axn[r] + vb_xn);
                ng[r] = fmaf(-2.0f,
                             __builtin_amdgcn_rcpf(__builtin_amdgcn_exp2f(y) + 1.0f),
                             1.0f);
            }
            __builtin_amdgcn_sched_barrier(0);

            // --- z-gate: MFMA chain, consume directly into h update ---
            const floatx4 az = MFMA16(Axx, Bz2, MFMA16(Ah1, Bz1, MFMA16(Ah0, Bz0, z4)));
            #pragma unroll
            for (int r = 0; r < 4; ++r) {
                const float zz = __builtin_amdgcn_rcpf(1.0f + __builtin_amdgcn_exp2f(az[r] + vb_z));
                const float h0 = h_reg[mt * 4 + r];
                h_reg[mt * 4 + r] = fmaf(zz, h0 - ng[r], ng[r]);  // (1-z)*ng + z*h
            }
        }
        __syncthreads();   // all waves' Hf reads complete -> in-place write safe
        short* HfW = &sm.g.Hf[hf_dir];
        #pragma unroll
        for (int mt = 0; mt < 2; ++mt) {
            #pragma unroll
            for (int r = 0; r < 4; ++r) {
                const int slot = qa_w * 16 + r * 4 + quad;   // perm of qa*16 + m
                HfW[((ks_w * 2 + mt) * 64 + slot) * 8 + ii_w] = f2bf_h(h_reg[mt * 4 + r]);
            }
        }
        __syncthreads();   // writes visible for next step
    }
    // Final h in Hf[dir]. Xall dead from here.

    // ---- re-gather scene into spatial union region (L2-hot; HBM idle) ----
    #pragma unroll
    for (int rep = 0; rep < 2; ++rep) {
        const int idx = tid + rep * 512;
        const int v = idx >> 5, c = idx & 31;
        const int n = index_div[g * NGRP + v];
        sm.s.sscene2[c][v] = scene[n * 32 + c];
    }
    __syncthreads();   // sscene2 ready

    // ---- Phase 2 prep: waves 0-3 seq_enc epilogue; waves 4-7 su/swo1/szero ----
    if (w < 4) {
        const int nt   = w >> 1;
        const int mt_e = w & 1;
        const int n_col = nt * 16 + cc;
        short8 Bm0, Bm1;
        #pragma unroll
        for (int i = 0; i < 8; ++i) {
            Bm0[i] = f2bf(Wm[(     quad * 8 + i) * 32 + n_col]);
            Bm1[i] = f2bf(Wm[(32 + quad * 8 + i) * 32 + n_col]);
        }
        short8 A0, A1;
        #pragma unroll
        for (int ks = 0; ks < 2; ++ks) {
            const short8 F = *(const short8*)&sm.g.Hf[0    + ((ks * 2 + mt_e) * 64 + rlane) * 8];
            const short8 B = *(const short8*)&sm.g.Hf[2048 + ((ks * 2 + mt_e) * 64 + rlane) * 8];
            #pragma unroll
            for (int i = 0; i < 8; ++i) {
                const short v = f2bf(0.5f * (bf2f(F[i]) + bf2f(B[i])));
                if (ks == 0) A0[i] = v; else A1[i] = v;
            }
        }
        const floatx4 z4 = {0.f, 0.f, 0.f, 0.f};
        const floatx4 acc = MFMA16(A1, Bm1, MFMA16(A0, Bm0, z4));
        const float bmn = bm[n_col];
        #pragma unroll
        for (int r = 0; r < 4; ++r) {
            const int veh = mt_e * 16 + quad * 4 + r;
            const float sv = leakyf(acc[r] + bmn);
            const int n = index_div[g * NGRP + veh];
            full_enc[n * HH + n_col] = sv;
            sm.s.fe[veh][n_col] = sv;     // fe region does not overlap Hf
        }
    } else {
        const int l  = tid & 255;
        const int v  = l >> 3;
        const int d0 = (l & 7) * 8;
        float acc[8];
        #pragma unroll
        for (int i = 0; i < 8; ++i) acc[i] = 0.0f;
        #pragma unroll
        for (int e = 0; e < EE; ++e) {
            const float f = sm.s.sscene2[e][v];
            const float4 w0 = *(const float4*)&Ws1[e * 64 + d0];
            const float4 w1 = *(const float4*)&Ws1[e * 64 + d0 + 4];
            acc[0] = fmaf(f, w0.x, acc[0]); acc[1] = fmaf(f, w0.y, acc[1]);
            acc[2] = fmaf(f, w0.z, acc[2]); acc[3] = fmaf(f, w0.w, acc[3]);
            acc[4] = fmaf(f, w1.x, acc[4]); acc[5] = fmaf(f, w1.y, acc[5]);
            acc[6] = fmaf(f, w1.z, acc[6]); acc[7] = fmaf(f, w1.w, acc[7]);
        }
        #pragma unroll
        for (int i = 0; i < 8; ++i) sm.s.su[v][d0 + i] = acc[i];
        *(float4*)&sm.s.swo1[l * 4] = *(const float4*)&Wo1[l * 4];
        if (l < 32) {
            float zs = bs2[l];
            #pragma unroll
            for (int d = 0; d < HH; ++d) zs = fmaf(leakyf(bs1[d]), Ws2[d * 32 + l], zs);
            sm.s.szero[l] = leakyf(zs);
        }
    }

    // ---- spatial B-frags (all 8 waves) ----
    short8 Bw00, Bw01, Bw10, Bw11;
    #pragma unroll
    for (int i = 0; i < 8; ++i) {
        Bw00[i] = f2bf(Ws2[(     quad * 8 + i) * 32 + cc]);
        Bw01[i] = f2bf(Ws2[(32 + quad * 8 + i) * 32 + cc]);
        Bw10[i] = f2bf(Ws2[(     quad * 8 + i) * 32 + 16 + cc]);
        Bw11[i] = f2bf(Ws2[(32 + quad * 8 + i) * 32 + 16 + cc]);
    }
    float bsq0[8], bsq1[8];
    #pragma unroll
    for (int i = 0; i < 8; ++i) {
        bsq0[i] = bs1[quad * 8 + i];
        bsq1[i] = bs1[32 + quad * 8 + i];
    }
    const float bs2c0 = bs2[cc], bs2c1 = bs2[16 + cc];
    __syncthreads();

    // ---- spatial pairwise MLP: 8 waves x 4 j's ----
    #pragma unroll 2
    for (int jj = 0; jj < 4; ++jj) {
        const int jrow = w * 4 + jj;       // wave-uniform j, 0..31
        float vj0[8], vj1[8];
        #pragma unroll
        for (int i = 0; i < 8; ++i) {
            vj0[i] = sm.s.su[jrow][quad * 8 + i] - bsq0[i];
            vj1[i] = sm.s.su[jrow][32 + quad * 8 + i] - bsq1[i];
        }
        float acc0 = 0.0f, acc1 = 0.0f;
        #pragma unroll
        for (int it = 0; it < 2; ++it) {
            const int irow = it * 16 + cc;   // A-frag row m = cc
            const float4 p0 = *(const float4*)&sm.s.su[irow][quad * 8];
            const float4 p1 = *(const float4*)&sm.s.su[irow][quad * 8 + 4];
            const float4 p2 = *(const float4*)&sm.s.su[irow][32 + quad * 8];
            const float4 p3 = *(const float4*)&sm.s.su[irow][32 + quad * 8 + 4];
            short8 A0, A1;
            A0[0] = f2bf(leakyf(p0.x - vj0[0])); A0[1] = f2bf(leakyf(p0.y - vj0[1]));
            A0[2] = f2bf(leakyf(p0.z - vj0[2])); A0[3] = f2bf(leakyf(p0.w - vj0[3]));
            A0[4] = f2bf(leakyf(p1.x - vj0[4])); A0[5] = f2bf(leakyf(p1.y - vj0[5]));
            A0[6] = f2bf(leakyf(p1.z - vj0[6])); A0[7] = f2bf(leakyf(p1.w - vj0[7]));
            A1[0] = f2bf(leakyf(p2.x - vj1[0])); A1[1] = f2bf(leakyf(p2.y - vj1[1]));
            A1[2] = f2bf(leakyf(p2.z - vj1[2])); A1[3] = f2bf(leakyf(p2.w - vj1[3]));
            A1[4] = f2bf(leakyf(p3.x - vj1[4])); A1[5] = f2bf(leakyf(p3.y - vj1[5]));
            A1[6] = f2bf(leakyf(p3.z - vj1[6])); A1[7] = f2bf(leakyf(p3.w - vj1[7]));
            const floatx4 z4 = {0.f, 0.f, 0.f, 0.f};
            const floatx4 D0 = MFMA16(A1, Bw01, MFMA16(A0, Bw00, z4));
            const floatx4 D1 = MFMA16(A1, Bw11, MFMA16(A0, Bw10, z4));
            #pragma unroll
            for (int r = 0; r < 4; ++r) {
                acc0 += leakyf(D0[r] + bs2c0);
                acc1 += leakyf(D1[r] + bs2c1);
            }
        }
        acc0 += __shfl_xor(acc0, 16, 64); acc0 += __shfl_xor(acc0, 32, 64);
        acc1 += __shfl_xor(acc1, 16, 64); acc1 += __shfl_xor(acc1, 32, 64);
        const int n = index_div[g * NGRP + jrow];
        if (quad == 0) {
            const float pv = (acc0 - sm.s.szero[cc]) * (1.0f / 31.0f);
            full_enc[n * HH + 32 + cc] = pv;
            sm.s.fe[jrow][32 + cc] = pv;
        } else if (quad == 1) {
            const float pv = (acc1 - sm.s.szero[16 + cc]) * (1.0f / 31.0f);
            full_enc[n * HH + 48 + cc] = pv;
            sm.s.fe[jrow][48 + cc] = pv;
        }
    }
    __syncthreads();

    // ---- head: x_logit = leaky(fe @ Wo1 + bo1) @ Wo2 + bo2 ----
    {
        const int veh = tid >> 4;          // 0..31
        const int p   = tid & 15;          // hidden dim
        float a = bo1[p];
        #pragma unroll
        for (int k = 0; k < HH; ++k)
            a = fmaf(sm.s.fe[veh][k], sm.s.swo1[k * 16 + p], a);
        a = leakyf(a);
        float l0 = a * Wo2[p * 3 + 0];
        float l1 = a * Wo2[p * 3 + 1];
        float l2 = a * Wo2[p * 3 + 2];
        #pragma unroll
        for (int off = 1; off < 16; off <<= 1) {
            l0 += __shfl_xor(l0, off, 64);
            l1 += __shfl_xor(l1, off, 64);
            l2 += __shfl_xor(l2, off, 64);
        }
        if (p == 0) {
            const int n = index_div[g * NGRP + veh];
            out[n * 3 + 0] = l0 + bo2[0];
            out[n * 3 + 1] = l1 + bo2[1];
            out[n * 3 + 2] = l2 + bo2[2];
        }
    }
}

// ---------------------------------------------------------------------------
extern "C" void kernel_launch(void* const* d_in, const int* in_sizes, int n_in,
                              void* d_out, int out_size, void* d_ws, size_t ws_size,
                              hipStream_t stream) {
    const float* scene     = (const float*)d_in[0];
    const int*   index_div = (const int*)d_in[4];
    const float* W_emb = (const float*)d_in[5];
    const float* b_emb = (const float*)d_in[6];
    const float* Wih_f = (const float*)d_in[7];
    const float* Whh_f = (const float*)d_in[8];
    const float* bih_f = (const float*)d_in[9];
    const float* bhh_f = (const float*)d_in[10];
    const float* Wih_b = (const float*)d_in[11];
    const float* Whh_b = (const float*)d_in[12];
    const float* bih_b = (const float*)d_in[13];
    const float* bhh_b = (const float*)d_in[14];
    const float* Wm  = (const float*)d_in[15];
    const float* bm  = (const float*)d_in[16];
    const float* Ws1 = (const float*)d_in[17];
    const float* bs1 = (const float*)d_in[18];
    const float* Ws2 = (const float*)d_in[19];
    const float* bs2 = (const float*)d_in[20];
    const float* Wo1 = (const float*)d_in[21];
    const float* bo1 = (const float*)d_in[22];
    const float* Wo2 = (const float*)d_in[23];
    const float* bo2 = (const float*)d_in[24];

    const int N = in_sizes[0] / (2 * TT);   // 32768
    const int G = in_sizes[4] / NGRP;       // 1024

    float* out      = (float*)d_out;
    float* full_enc = out + (size_t)N * CC;

    fused_kernel<<<dim3(G), dim3(512), 0, stream>>>(
        scene, index_div, W_emb, b_emb, Wih_f, Whh_f, bih_f, bhh_f,
        Wih_b, Whh_b, bih_b, bhh_b, Wm, bm, Ws1, bs1, Ws2, bs2,
        Wo1, bo1, Wo2, bo2, full_enc, out);
}

// Round 8
// 207.758 us; speedup vs baseline: 1.1101x; 1.0291x over previous
//
#include <hip/hip_runtime.h>
#include <hip/hip_bf16.h>

#define TT 16      // in_length
#define EE 32      // embedding size
#define HH 64      // encoder size
#define NGRP 32    // vehicles per group
#define CC 3       // classes

typedef __attribute__((ext_vector_type(8))) short short8;
typedef __attribute__((ext_vector_type(4))) float floatx4;

#define MFMA16(a, b, c) __builtin_amdgcn_mfma_f32_16x16x32_bf16((a), (b), (c), 0, 0, 0)

#define RLN2 1.4426950408889634f   // 1/ln2

__device__ __forceinline__ float leakyf(float x) { return fmaxf(x, 0.1f * x); }
__device__ __forceinline__ short f2bf(float x) {   // fp32 -> bf16 RNE (one-time weights)
    unsigned u = __float_as_uint(x);
    return (short)((u + 0x7FFFu + ((u >> 16) & 1u)) >> 16);
}
__device__ __forceinline__ short f2bf_h(float x) { // fp32 -> bf16 round-half-up (per-step)
    return (short)((__float_as_uint(x) + 0x8000u) >> 16);
}
__device__ __forceinline__ float bf2f(short s) {
    return __uint_as_float(((unsigned)(unsigned short)s) << 16);
}
__device__ __forceinline__ short8 ld8bfs(const float* __restrict__ p, float s) {
    const float4 a = *(const float4*)p;
    const float4 b = *(const float4*)(p + 4);
    short8 v;
    v[0] = f2bf(a.x * s); v[1] = f2bf(a.y * s); v[2] = f2bf(a.z * s); v[3] = f2bf(a.w * s);
    v[4] = f2bf(b.x * s); v[5] = f2bf(b.y * s); v[6] = f2bf(b.z * s); v[7] = f2bf(b.w * s);
    return v;
}

// ---------------------------------------------------------------------------
// R15 = R14 with the union-overlap bug FIXED.
// R14's NaN root cause: adding su_mb grew the spatial struct to 34560 B,
// pushing sscene2 into [30336,34560) which overlaps live Hf [32768,40960).
// The post-GRU scene re-gather clobbered fwd-dir h before the seq_enc
// epilogue read it -> NaN. Fix: DROP su_mb (restore bsq register arrays in
// the spatial phase); spatial struct back to 25856 B < 32768 = Xall size,
// restoring the "spatial union must end below Hf" invariant.
//
// Carried from R14 (perf structure, never falsified):
//   * prep_kernel packs all 8 waves' 9 GRU B-frags (bf16, MFMA lane layout,
//     pre-scaled) into d_ws (73728 B, L2-resident).
//   * GRU step streams frags on demand (1 dwordx4/frag): n-frags at step
//     top, z-frags after phase-n, next-step r-frags after phase-z (in
//     flight across the barrier). Pointer laundered per-iter (asm "+v")
//     to defeat LICM re-hoisting into persistent regs.
//   * Phases serialized ACROSS the mt pair (r both mts -> n -> z); A-frags
//     re-read from LDS per phase (Hf only written after the end-of-step
//     barrier -> values identical). Peak live ~74-80 <= (512,6) budget.
// All per-element arithmetic unchanged -> absmax must stay 0.015625.
// Sentinel: FETCH > 15MB => (512,6) unreachable, revert to R2/107 config.
// ---------------------------------------------------------------------------
__global__ __launch_bounds__(512) void prep_kernel(
    const float* __restrict__ Wih_f, const float* __restrict__ Whh_f,
    const float* __restrict__ Wih_b, const float* __restrict__ Whh_b,
    short* __restrict__ wsf)
{
    const int tid  = threadIdx.x;         // 512 = 8 "waves" x 64 lanes
    const int widx = tid >> 6;
    const int lane = tid & 63;
    const int dir  = widx >> 2;
    const int wd   = widx & 3;
    const int cc   = lane & 15;
    const int quad = lane >> 4;
    const int j    = wd * 16 + cc;
    const int k0   = quad * 8;
    const float* Wih = dir ? Wih_b : Wih_f;
    const float* Whh = dir ? Whh_b : Whh_f;
    const float SRZ = -RLN2, SN = 2.0f * RLN2;
    short8 f[9];
    f[0] = ld8bfs(Whh + (j      ) * 64 + k0,      SRZ);   // Br0
    f[1] = ld8bfs(Whh + (j      ) * 64 + 32 + k0, SRZ);   // Br1
    f[2] = ld8bfs(Wih + (j      ) * 32 + k0,      SRZ);   // Br2
    f[3] = ld8bfs(Whh + (j +  64) * 64 + k0,      SRZ);   // Bz0
    f[4] = ld8bfs(Whh + (j +  64) * 64 + 32 + k0, SRZ);   // Bz1
    f[5] = ld8bfs(Wih + (j +  64) * 32 + k0,      SRZ);   // Bz2
    f[6] = ld8bfs(Whh + (j + 128) * 64 + k0,      SN);    // Bhn0
    f[7] = ld8bfs(Whh + (j + 128) * 64 + 32 + k0, SN);    // Bhn1
    f[8] = ld8bfs(Wih + (j + 128) * 32 + k0,      SN);    // Bxn
    #pragma unroll
    for (int fid = 0; fid < 9; ++fid)
        *(short8*)&wsf[((widx * 9 + fid) * 64 + lane) * 8] = f[fid];
}

__global__ __launch_bounds__(512, 6) void fused_kernel(
    const float* __restrict__ scene, const int* __restrict__ index_div,
    const float* __restrict__ W_emb, const float* __restrict__ b_emb,
    const float* __restrict__ bih_f, const float* __restrict__ bhh_f,
    const float* __restrict__ bih_b, const float* __restrict__ bhh_b,
    const float* __restrict__ Wm, const float* __restrict__ bm,
    const float* __restrict__ Ws1, const float* __restrict__ bs1,
    const float* __restrict__ Ws2, const float* __restrict__ bs2,
    const float* __restrict__ Wo1, const float* __restrict__ bo1,
    const float* __restrict__ Wo2, const float* __restrict__ bo2,
    const short* __restrict__ wsf,
    float* __restrict__ full_enc, float* __restrict__ out)
{
    __shared__ __align__(16) union SmemU {
        struct {                                     // GRU phase: 40960 B exactly
            short Xall[16 * 2 * 64 * 8];             // [t][mt][lane][8]      32768 B
            short Hf[2 * 2 * 2 * 64 * 8];            // [dir][ks][mt][slot][8] 8192 B (single buf)
        } g;
        struct {                                     // spatial/head phase: 25856 B < 32768 B
            float su[NGRP][68];                      //  8704 B  [    0,  8704)
            float fe[NGRP][68];                      //  8704 B  [ 8704, 17408)
            float swo1[1024];                        //  4096 B  [17408, 21504)
            float szero[32];                         //   128 B  [21504, 21632)
            float sscene2[32][33];                   //  4224 B  [21632, 25856)  < 32768: no Hf overlap
        } s;
    } sm;

    const int g    = blockIdx.x;
    const int tid  = threadIdx.x;
    const int lane = tid & 63;
    const int w    = __builtin_amdgcn_readfirstlane(tid >> 6);  // 0..7
    const int dir  = w >> 2;
    const int wd   = w & 3;
    const int cc   = lane & 15;
    const int quad = lane >> 4;
    const int j    = wd * 16 + cc;            // gate column
    const int ks_w = j >> 5;
    const int qa_w = (j >> 3) & 3;
    const int ii_w = j & 7;
    // permuted reader lane: slot(Lq, m) = Lq*16 + (m&3)*4 + (m>>2)
    const int rlane = (lane & 48) | ((lane & 3) << 2) | ((lane >> 2) & 3);

    // ---- stage gathered scene rows into the (not-yet-live) Hf bytes ----
    {
        float* sc0 = (float*)sm.g.Hf;
        #pragma unroll
        for (int rep = 0; rep < 2; ++rep) {
            const int idx = tid + rep * 512;
            const int v = idx >> 5, c = idx & 31;
            const int n = index_div[g * NGRP + v];
            sc0[c * 33 + v] = scene[n * 32 + c];
        }
    }

    // ---- per-lane gate biases (pre-scaled, scalar) ----
    const float* bih = dir ? bih_b : bih_f;
    const float* bhh = dir ? bhh_b : bhh_f;
    const float SRZ = -RLN2, SN = 2.0f * RLN2;
    const float vb_r  = SRZ * (bih[j] + bhh[j]);
    const float vb_z  = SRZ * (bih[j + 64] + bhh[j + 64]);
    const float vb_xn = SN * bih[j + 128];
    const float vb_hn = SN * bhh[j + 128];

    __syncthreads();   // sc0 ready

    // ---- emb for ALL t; writes Xall. Barrier, THEN zero Hf. ----
    {
        const float* sc0 = (const float*)sm.g.Hf;
        const int t   = tid >> 5;
        const int veh = tid & 31;
        const float xs = sc0[t * 33 + veh];
        const float ys = sc0[(16 + t) * 33 + veh];
        const int mt = veh >> 4;
        const int m  = veh & 15;
        #pragma unroll
        for (int q = 0; q < 4; ++q) {
            short8 v;
            #pragma unroll
            for (int i2 = 0; i2 < 8; ++i2) {
                const int e = q * 8 + i2;
                v[i2] = f2bf(leakyf(fmaf(xs, W_emb[e], fmaf(ys, W_emb[EE + e], b_emb[e]))));
            }
            *(short8*)&sm.g.Xall[(((t * 2 + mt) * 64) + q * 16 + m) * 8] = v;
        }
    }
    __syncthreads();   // all sc0 reads consumed -> Hf bytes reusable
    {
        const short8 z8 = {0, 0, 0, 0, 0, 0, 0, 0};
        *(short8*)&sm.g.Hf[tid * 8] = z8;
    }

    float h_reg[8];
    #pragma unroll
    for (int i = 0; i < 8; ++i) h_reg[i] = 0.0f;

    const int hf_dir = dir * 2048;                 // shorts (dir stride, single buf)
    __syncthreads();   // Hf zeroed

    // ---- GRU main loop: streamed B-frags, phase-serialized across mt ----
    const short* pB = wsf + ((size_t)(w * 9) * 64 + lane) * 8;
    short8 BrA = *(const short8*)(pB + 0 * 512);   // prologue r-frags
    short8 BrB = *(const short8*)(pB + 1 * 512);
    short8 BrC = *(const short8*)(pB + 2 * 512);
    float rr[8], ng[8];

    #pragma unroll 1
    for (int s = 0; s < TT; ++s) {
        asm("" : "+v"(pB));                        // defeat LICM: opaque per-iter
        const short8 Bn0 = *(const short8*)(pB + 6 * 512);   // n-frags in flight
        const short8 Bn1 = *(const short8*)(pB + 7 * 512);
        const short8 Bn2 = *(const short8*)(pB + 8 * 512);
        const int t  = dir ? (TT - 1 - s) : s;
        const short* HfD = &sm.g.Hf[hf_dir];
        const floatx4 z4 = {0.f, 0.f, 0.f, 0.f};

        // --- phase r (both mts); A-frags die within each mt sub-block ---
        #pragma unroll
        for (int mt = 0; mt < 2; ++mt) {
            const short8 Ah0 = *(const short8*)&HfD[((0 * 2 + mt) * 64 + rlane) * 8];
            const short8 Ah1 = *(const short8*)&HfD[((1 * 2 + mt) * 64 + rlane) * 8];
            const short8 Axx = *(const short8*)&sm.g.Xall[((t * 2 + mt) * 64 + lane) * 8];
            const floatx4 ar = MFMA16(Axx, BrC, MFMA16(Ah1, BrB, MFMA16(Ah0, BrA, z4)));
            #pragma unroll
            for (int r = 0; r < 4; ++r)
                rr[mt * 4 + r] =
                    __builtin_amdgcn_rcpf(1.0f + __builtin_amdgcn_exp2f(ar[r] + vb_r));
        }
        __builtin_amdgcn_sched_barrier(0);

        // --- phase n (both mts) ---
        #pragma unroll
        for (int mt = 0; mt < 2; ++mt) {
            const short8 Ah0 = *(const short8*)&HfD[((0 * 2 + mt) * 64 + rlane) * 8];
            const short8 Ah1 = *(const short8*)&HfD[((1 * 2 + mt) * 64 + rlane) * 8];
            const short8 Axx = *(const short8*)&sm.g.Xall[((t * 2 + mt) * 64 + lane) * 8];
            const floatx4 ahn = MFMA16(Ah1, Bn1, MFMA16(Ah0, Bn0, z4));
            const floatx4 axn = MFMA16(Axx, Bn2, z4);
            #pragma unroll
            for (int r = 0; r < 4; ++r) {
                const float y = fmaf(rr[mt * 4 + r], ahn[r] + vb_hn, axn[r] + vb_xn);
                ng[mt * 4 + r] = fmaf(-2.0f,
                                      __builtin_amdgcn_rcpf(__builtin_amdgcn_exp2f(y) + 1.0f),
                                      1.0f);
            }
        }
        __builtin_amdgcn_sched_barrier(0);

        // --- phase z (both mts); z-frags loaded here ---
        {
            const short8 Bz0 = *(const short8*)(pB + 3 * 512);
            const short8 Bz1 = *(const short8*)(pB + 4 * 512);
            const short8 Bz2 = *(const short8*)(pB + 5 * 512);
            #pragma unroll
            for (int mt = 0; mt < 2; ++mt) {
                const short8 Ah0 = *(const short8*)&HfD[((0 * 2 + mt) * 64 + rlane) * 8];
                const short8 Ah1 = *(const short8*)&HfD[((1 * 2 + mt) * 64 + rlane) * 8];
                const short8 Axx = *(const short8*)&sm.g.Xall[((t * 2 + mt) * 64 + lane) * 8];
                const floatx4 az = MFMA16(Axx, Bz2, MFMA16(Ah1, Bz1, MFMA16(Ah0, Bz0, z4)));
                #pragma unroll
                for (int r = 0; r < 4; ++r) {
                    const float zz =
                        __builtin_amdgcn_rcpf(1.0f + __builtin_amdgcn_exp2f(az[r] + vb_z));
                    const float h0 = h_reg[mt * 4 + r];
                    h_reg[mt * 4 + r] = fmaf(zz, h0 - ng[mt * 4 + r], ng[mt * 4 + r]);
                }
            }
        }
        // next-step r-frags: in flight across the barrier (same addresses)
        BrA = *(const short8*)(pB + 0 * 512);
        BrB = *(const short8*)(pB + 1 * 512);
        BrC = *(const short8*)(pB + 2 * 512);

        __syncthreads();   // all waves' Hf reads complete -> in-place write safe
        short* HfW = &sm.g.Hf[hf_dir];
        #pragma unroll
        for (int mt = 0; mt < 2; ++mt) {
            #pragma unroll
            for (int r = 0; r < 4; ++r) {
                const int slot = qa_w * 16 + r * 4 + quad;   // perm of qa*16 + m
                HfW[((ks_w * 2 + mt) * 64 + slot) * 8 + ii_w] = f2bf_h(h_reg[mt * 4 + r]);
            }
        }
        __syncthreads();   // writes visible for next step
    }
    // Final h in Hf[dir]. Xall dead from here.

    // ---- re-gather scene into spatial union region (L2-hot; < Hf offset) ----
    #pragma unroll
    for (int rep = 0; rep < 2; ++rep) {
        const int idx = tid + rep * 512;
        const int v = idx >> 5, c = idx & 31;
        const int n = index_div[g * NGRP + v];
        sm.s.sscene2[c][v] = scene[n * 32 + c];
    }
    __syncthreads();   // sscene2 ready

    // ---- Phase 2 prep: waves 0-3 seq_enc epilogue; waves 4-7 su/swo1/szero ----
    if (w < 4) {
        const int nt   = w >> 1;
        const int mt_e = w & 1;
        const int n_col = nt * 16 + cc;
        short8 Bm0, Bm1;
        #pragma unroll
        for (int i = 0; i < 8; ++i) {
            Bm0[i] = f2bf(Wm[(     quad * 8 + i) * 32 + n_col]);
            Bm1[i] = f2bf(Wm[(32 + quad * 8 + i) * 32 + n_col]);
        }
        short8 A0, A1;
        #pragma unroll
        for (int ks = 0; ks < 2; ++ks) {
            const short8 F = *(const short8*)&sm.g.Hf[0    + ((ks * 2 + mt_e) * 64 + rlane) * 8];
            const short8 B = *(const short8*)&sm.g.Hf[2048 + ((ks * 2 + mt_e) * 64 + rlane) * 8];
            #pragma unroll
            for (int i = 0; i < 8; ++i) {
                const short v = f2bf(0.5f * (bf2f(F[i]) + bf2f(B[i])));
                if (ks == 0) A0[i] = v; else A1[i] = v;
            }
        }
        const floatx4 z4 = {0.f, 0.f, 0.f, 0.f};
        const floatx4 acc = MFMA16(A1, Bm1, MFMA16(A0, Bm0, z4));
        const float bmn = bm[n_col];
        #pragma unroll
        for (int r = 0; r < 4; ++r) {
            const int veh = mt_e * 16 + quad * 4 + r;
            const float sv = leakyf(acc[r] + bmn);
            const int n = index_div[g * NGRP + veh];
            full_enc[n * HH + n_col] = sv;
            sm.s.fe[veh][n_col] = sv;     // fe at [8704,17408): no Hf overlap
        }
    } else {
        const int l  = tid & 255;
        const int v  = l >> 3;
        const int d0 = (l & 7) * 8;
        float acc[8];
        #pragma unroll
        for (int i = 0; i < 8; ++i) acc[i] = 0.0f;
        #pragma unroll
        for (int e = 0; e < EE; ++e) {
            const float f = sm.s.sscene2[e][v];
            const float4 w0 = *(const float4*)&Ws1[e * 64 + d0];
            const float4 w1 = *(const float4*)&Ws1[e * 64 + d0 + 4];
            acc[0] = fmaf(f, w0.x, acc[0]); acc[1] = fmaf(f, w0.y, acc[1]);
            acc[2] = fmaf(f, w0.z, acc[2]); acc[3] = fmaf(f, w0.w, acc[3]);
            acc[4] = fmaf(f, w1.x, acc[4]); acc[5] = fmaf(f, w1.y, acc[5]);
            acc[6] = fmaf(f, w1.z, acc[6]); acc[7] = fmaf(f, w1.w, acc[7]);
        }
        #pragma unroll
        for (int i = 0; i < 8; ++i) sm.s.su[v][d0 + i] = acc[i];
        *(float4*)&sm.s.swo1[l * 4] = *(const float4*)&Wo1[l * 4];
        if (l < 32) {
            float zs = bs2[l];
            #pragma unroll
            for (int d = 0; d < HH; ++d) zs = fmaf(leakyf(bs1[d]), Ws2[d * 32 + l], zs);
            sm.s.szero[l] = leakyf(zs);
        }
    }

    // ---- spatial B-frags (all 8 waves) ----
    short8 Bw00, Bw01, Bw10, Bw11;
    #pragma unroll
    for (int i = 0; i < 8; ++i) {
        Bw00[i] = f2bf(Ws2[(     quad * 8 + i) * 32 + cc]);
        Bw01[i] = f2bf(Ws2[(32 + quad * 8 + i) * 32 + cc]);
        Bw10[i] = f2bf(Ws2[(     quad * 8 + i) * 32 + 16 + cc]);
        Bw11[i] = f2bf(Ws2[(32 + quad * 8 + i) * 32 + 16 + cc]);
    }
    float bsq0[8], bsq1[8];
    #pragma unroll
    for (int i = 0; i < 8; ++i) {
        bsq0[i] = bs1[quad * 8 + i];
        bsq1[i] = bs1[32 + quad * 8 + i];
    }
    const float bs2c0 = bs2[cc], bs2c1 = bs2[16 + cc];
    __syncthreads();

    // ---- spatial pairwise MLP: 8 waves x 4 j's ----
    #pragma unroll 2
    for (int jj = 0; jj < 4; ++jj) {
        const int jrow = w * 4 + jj;       // wave-uniform j, 0..31
        float vj0[8], vj1[8];
        #pragma unroll
        for (int i = 0; i < 8; ++i) {
            vj0[i] = sm.s.su[jrow][quad * 8 + i] - bsq0[i];
            vj1[i] = sm.s.su[jrow][32 + quad * 8 + i] - bsq1[i];
        }
        float acc0 = 0.0f, acc1 = 0.0f;
        #pragma unroll
        for (int it = 0; it < 2; ++it) {
            const int irow = it * 16 + cc;   // A-frag row m = cc
            const float4 p0 = *(const float4*)&sm.s.su[irow][quad * 8];
            const float4 p1 = *(const float4*)&sm.s.su[irow][quad * 8 + 4];
            const float4 p2 = *(const float4*)&sm.s.su[irow][32 + quad * 8];
            const float4 p3 = *(const float4*)&sm.s.su[irow][32 + quad * 8 + 4];
            short8 A0, A1;
            A0[0] = f2bf(leakyf(p0.x - vj0[0])); A0[1] = f2bf(leakyf(p0.y - vj0[1]));
            A0[2] = f2bf(leakyf(p0.z - vj0[2])); A0[3] = f2bf(leakyf(p0.w - vj0[3]));
            A0[4] = f2bf(leakyf(p1.x - vj0[4])); A0[5] = f2bf(leakyf(p1.y - vj0[5]));
            A0[6] = f2bf(leakyf(p1.z - vj0[6])); A0[7] = f2bf(leakyf(p1.w - vj0[7]));
            A1[0] = f2bf(leakyf(p2.x - vj1[0])); A1[1] = f2bf(leakyf(p2.y - vj1[1]));
            A1[2] = f2bf(leakyf(p2.z - vj1[2])); A1[3] = f2bf(leakyf(p2.w - vj1[3]));
            A1[4] = f2bf(leakyf(p3.x - vj1[4])); A1[5] = f2bf(leakyf(p3.y - vj1[5]));
            A1[6] = f2bf(leakyf(p3.z - vj1[6])); A1[7] = f2bf(leakyf(p3.w - vj1[7]));
            const floatx4 z4 = {0.f, 0.f, 0.f, 0.f};
            const floatx4 D0 = MFMA16(A1, Bw01, MFMA16(A0, Bw00, z4));
            const floatx4 D1 = MFMA16(A1, Bw11, MFMA16(A0, Bw10, z4));
            #pragma unroll
            for (int r = 0; r < 4; ++r) {
                acc0 += leakyf(D0[r] + bs2c0);
                acc1 += leakyf(D1[r] + bs2c1);
            }
        }
        acc0 += __shfl_xor(acc0, 16, 64); acc0 += __shfl_xor(acc0, 32, 64);
        acc1 += __shfl_xor(acc1, 16, 64); acc1 += __shfl_xor(acc1, 32, 64);
        const int n = index_div[g * NGRP + jrow];
        if (quad == 0) {
            const float pv = (acc0 - sm.s.szero[cc]) * (1.0f / 31.0f);
            full_enc[n * HH + 32 + cc] = pv;
            sm.s.fe[jrow][32 + cc] = pv;
        } else if (quad == 1) {
            const float pv = (acc1 - sm.s.szero[16 + cc]) * (1.0f / 31.0f);
            full_enc[n * HH + 48 + cc] = pv;
            sm.s.fe[jrow][48 + cc] = pv;
        }
    }
    __syncthreads();

    // ---- head: x_logit = leaky(fe @ Wo1 + bo1) @ Wo2 + bo2 ----
    {
        const int veh = tid >> 4;          // 0..31
        const int p   = tid & 15;          // hidden dim
        float a = bo1[p];
        #pragma unroll
        for (int k = 0; k < HH; ++k)
            a = fmaf(sm.s.fe[veh][k], sm.s.swo1[k * 16 + p], a);
        a = leakyf(a);
        float l0 = a * Wo2[p * 3 + 0];
        float l1 = a * Wo2[p * 3 + 1];
        float l2 = a * Wo2[p * 3 + 2];
        #pragma unroll
        for (int off = 1; off < 16; off <<= 1) {
            l0 += __shfl_xor(l0, off, 64);
            l1 += __shfl_xor(l1, off, 64);
            l2 += __shfl_xor(l2, off, 64);
        }
        if (p == 0) {
            const int n = index_div[g * NGRP + veh];
            out[n * 3 + 0] = l0 + bo2[0];
            out[n * 3 + 1] = l1 + bo2[1];
            out[n * 3 + 2] = l2 + bo2[2];
        }
    }
}

// ---------------------------------------------------------------------------
extern "C" void kernel_launch(void* const* d_in, const int* in_sizes, int n_in,
                              void* d_out, int out_size, void* d_ws, size_t ws_size,
                              hipStream_t stream) {
    const float* scene     = (const float*)d_in[0];
    const int*   index_div = (const int*)d_in[4];
    const float* W_emb = (const float*)d_in[5];
    const float* b_emb = (const float*)d_in[6];
    const float* Wih_f = (const float*)d_in[7];
    const float* Whh_f = (const float*)d_in[8];
    const float* bih_f = (const float*)d_in[9];
    const float* bhh_f = (const float*)d_in[10];
    const float* Wih_b = (const float*)d_in[11];
    const float* Whh_b = (const float*)d_in[12];
    const float* bih_b = (const float*)d_in[13];
    const float* bhh_b = (const float*)d_in[14];
    const float* Wm  = (const float*)d_in[15];
    const float* bm  = (const float*)d_in[16];
    const float* Ws1 = (const float*)d_in[17];
    const float* bs1 = (const float*)d_in[18];
    const float* Ws2 = (const float*)d_in[19];
    const float* bs2 = (const float*)d_in[20];
    const float* Wo1 = (const float*)d_in[21];
    const float* bo1 = (const float*)d_in[22];
    const float* Wo2 = (const float*)d_in[23];
    const float* bo2 = (const float*)d_in[24];

    const int N = in_sizes[0] / (2 * TT);   // 32768
    const int G = in_sizes[4] / NGRP;       // 1024

    float* out      = (float*)d_out;
    float* full_enc = out + (size_t)N * CC;
    short* wsf      = (short*)d_ws;         // 73728 B frag buffer

    prep_kernel<<<dim3(1), dim3(512), 0, stream>>>(
        Wih_f, Whh_f, Wih_b, Whh_b, wsf);

    fused_kernel<<<dim3(G), dim3(512), 0, stream>>>(
        scene, index_div, W_emb, b_emb, bih_f, bhh_f, bih_b, bhh_b,
        Wm, bm, Ws1, bs1, Ws2, bs2, Wo1, bo1, Wo2, bo2, wsf,
        full_enc, out);
}